// Round 1
// baseline (40.019 us; speedup 1.0000x reference)
//
#include <hip/hip_runtime.h>

// SeparableConvFlowLayer forward:
//   flow_x[b,h,w] = sum_f in3[b,f,h,w]*f / sum_f in3[b,f,h,w] - 25
//   flow_y[b,h,w] = sum_f in2[b,f,h,w]*f / sum_f in2[b,f,h,w] - 25
//   out = stack([flow_x, flow_y], axis=1)  -> [B,2,H,W] f32
// input1 is unused by the reference -> never read it.

constexpr int Bn = 4;
constexpr int Fn = 51;
constexpr int Hn = 384;
constexpr int Wn = 384;
constexpr int HW = Hn * Wn;     // 147456 (divisible by 4)
constexpr int PIX = Bn * HW;    // 589824

__global__ __launch_bounds__(256) void separable_conv_flow_kernel(
    const float* __restrict__ in2,   // [B,F,H,W] vertical taps  -> flow_y
    const float* __restrict__ in3,   // [B,F,H,W] horizontal taps -> flow_x
    float* __restrict__ out)         // [B,2,H,W]
{
    const int t = blockIdx.x * blockDim.x + threadIdx.x;
    const int p4 = t * 4;                    // first of 4 consecutive pixels
    if (p4 >= PIX) return;

    const int b   = p4 / HW;
    const int off = p4 - b * HW;             // within-image flat offset (h*W + w)

    const float4* __restrict__ v2 =
        reinterpret_cast<const float4*>(in2 + (size_t)b * Fn * HW + off);
    const float4* __restrict__ v3 =
        reinterpret_cast<const float4*>(in3 + (size_t)b * Fn * HW + off);

    float4 s2 = make_float4(0.f, 0.f, 0.f, 0.f);  // sum in2
    float4 m2 = make_float4(0.f, 0.f, 0.f, 0.f);  // sum in2*f
    float4 s3 = make_float4(0.f, 0.f, 0.f, 0.f);  // sum in3
    float4 m3 = make_float4(0.f, 0.f, 0.f, 0.f);  // sum in3*f

    constexpr int stride4 = HW / 4;          // float4 stride between f-slices

    #pragma unroll 8
    for (int f = 0; f < Fn; ++f) {
        const float4 a = v2[(size_t)f * stride4];
        const float4 c = v3[(size_t)f * stride4];
        const float ff = (float)f;
        s2.x += a.x; s2.y += a.y; s2.z += a.z; s2.w += a.w;
        m2.x = fmaf(a.x, ff, m2.x); m2.y = fmaf(a.y, ff, m2.y);
        m2.z = fmaf(a.z, ff, m2.z); m2.w = fmaf(a.w, ff, m2.w);
        s3.x += c.x; s3.y += c.y; s3.z += c.z; s3.w += c.w;
        m3.x = fmaf(c.x, ff, m3.x); m3.y = fmaf(c.y, ff, m3.y);
        m3.z = fmaf(c.z, ff, m3.z); m3.w = fmaf(c.w, ff, m3.w);
    }

    const float center = (float)(Fn - 1) * 0.5f;   // 25.0
    float4 fx, fy;
    fx.x = m3.x / s3.x - center; fx.y = m3.y / s3.y - center;
    fx.z = m3.z / s3.z - center; fx.w = m3.w / s3.w - center;
    fy.x = m2.x / s2.x - center; fy.y = m2.y / s2.y - center;
    fy.z = m2.z / s2.z - center; fy.w = m2.w / s2.w - center;

    float4* __restrict__ o = reinterpret_cast<float4*>(out);
    const int obase = b * 2 * (HW / 4);      // start of this batch's [2,H,W] block
    const int o4    = off / 4;
    o[obase + o4]            = fx;           // channel 0: flow_x
    o[obase + (HW / 4) + o4] = fy;           // channel 1: flow_y
}

extern "C" void kernel_launch(void* const* d_in, const int* in_sizes, int n_in,
                              void* d_out, int out_size, void* d_ws, size_t ws_size,
                              hipStream_t stream) {
    // d_in[0] = input1 [B,C,H,W]  (unused)
    // d_in[1] = input2 [B,F,H,W]  (vertical taps -> flow_y)
    // d_in[2] = input3 [B,F,H,W]  (horizontal taps -> flow_x)
    const float* in2 = (const float*)d_in[1];
    const float* in3 = (const float*)d_in[2];
    float* out = (float*)d_out;

    constexpr int threads = 256;
    constexpr int nthreads_total = PIX / 4;              // 147456
    constexpr int blocks = (nthreads_total + threads - 1) / threads;  // 576

    separable_conv_flow_kernel<<<blocks, threads, 0, stream>>>(in2, in3, out);
}

// Round 2
// 39.843 us; speedup vs baseline: 1.0044x; 1.0044x over previous
//
#include <hip/hip_runtime.h>

// SeparableConvFlowLayer forward:
//   flow_x[b,h,w] = sum_f in3[b,f,h,w]*f / sum_f in3[b,f,h,w] - 25
//   flow_y[b,h,w] = sum_f in2[b,f,h,w]*f / sum_f in2[b,f,h,w] - 25
//   out = stack([flow_x, flow_y], axis=1)  -> [B,2,H,W] f32
// input1 is unused by the reference -> never read it.
//
// R1: split the two independent tap-reductions across gridDim.y to double
// wave count (2304 -> 4608 waves); kernel was latency-limited at 22% occupancy
// with ~50% of reads served by Infinity Cache.

constexpr int Bn = 4;
constexpr int Fn = 51;
constexpr int Hn = 384;
constexpr int Wn = 384;
constexpr int HW = Hn * Wn;     // 147456 (divisible by 4)
constexpr int PIX = Bn * HW;    // 589824

__global__ __launch_bounds__(256) void separable_conv_flow_kernel(
    const float* __restrict__ in2,   // [B,F,H,W] vertical taps  -> flow_y (ch 1)
    const float* __restrict__ in3,   // [B,F,H,W] horizontal taps -> flow_x (ch 0)
    float* __restrict__ out)         // [B,2,H,W]
{
    const int t  = blockIdx.x * blockDim.x + threadIdx.x;
    const int ch = blockIdx.y;               // 0: flow_x (in3), 1: flow_y (in2)
    const int p4 = t * 4;                    // first of 4 consecutive pixels
    if (p4 >= PIX) return;

    const int b   = p4 / HW;
    const int off = p4 - b * HW;             // within-image flat offset (h*W + w)

    const float* __restrict__ src = (ch == 0) ? in3 : in2;  // wave-uniform
    const float4* __restrict__ v =
        reinterpret_cast<const float4*>(src + (size_t)b * Fn * HW + off);

    float4 s = make_float4(0.f, 0.f, 0.f, 0.f);  // sum w
    float4 m = make_float4(0.f, 0.f, 0.f, 0.f);  // sum w*f

    constexpr int stride4 = HW / 4;          // float4 stride between f-slices

    #pragma unroll 8
    for (int f = 0; f < Fn; ++f) {
        const float4 a = v[(size_t)f * stride4];
        const float ff = (float)f;
        s.x += a.x; s.y += a.y; s.z += a.z; s.w += a.w;
        m.x = fmaf(a.x, ff, m.x); m.y = fmaf(a.y, ff, m.y);
        m.z = fmaf(a.z, ff, m.z); m.w = fmaf(a.w, ff, m.w);
    }

    const float center = (float)(Fn - 1) * 0.5f;   // 25.0
    float4 r;
    r.x = m.x / s.x - center; r.y = m.y / s.y - center;
    r.z = m.z / s.z - center; r.w = m.w / s.w - center;

    float4* __restrict__ o = reinterpret_cast<float4*>(out);
    const int obase = b * 2 * (HW / 4);      // start of this batch's [2,H,W] block
    o[obase + ch * (HW / 4) + off / 4] = r;
}

extern "C" void kernel_launch(void* const* d_in, const int* in_sizes, int n_in,
                              void* d_out, int out_size, void* d_ws, size_t ws_size,
                              hipStream_t stream) {
    // d_in[0] = input1 [B,C,H,W]  (unused)
    // d_in[1] = input2 [B,F,H,W]  (vertical taps -> flow_y)
    // d_in[2] = input3 [B,F,H,W]  (horizontal taps -> flow_x)
    const float* in2 = (const float*)d_in[1];
    const float* in3 = (const float*)d_in[2];
    float* out = (float*)d_out;

    constexpr int threads = 256;
    constexpr int nthreads_total = PIX / 4;              // 147456
    constexpr int blocks_x = (nthreads_total + threads - 1) / threads;  // 576

    dim3 grid(blocks_x, 2, 1);
    separable_conv_flow_kernel<<<grid, threads, 0, stream>>>(in2, in3, out);
}